// Round 3
// baseline (193.611 us; speedup 1.0000x reference)
//
#include <hip/hip_runtime.h>
#include <stdint.h>
#include <stddef.h>

typedef __attribute__((ext_vector_type(8))) short short8;
typedef __attribute__((ext_vector_type(4))) float f32x4;
typedef __attribute__((ext_vector_type(16))) float f32x16;
typedef __attribute__((ext_vector_type(4))) unsigned short ushort4v;
typedef __attribute__((ext_vector_type(4))) unsigned int uint4v;

#define SEQ   2048
#define NH    16
#define BATCH 4
#define GK    1024

__device__ __forceinline__ unsigned short f2bf(float f) {
  union { float f; unsigned int u; } v; v.f = f;
  unsigned int u = v.u;
  u += 0x7fffu + ((u >> 16) & 1u);
  return (unsigned short)(u >> 16);
}

__device__ __forceinline__ unsigned cvtpk_bf16(float lo, float hi) {
  unsigned r;
  asm("v_cvt_pk_bf16_f32 %0, %1, %2" : "=v"(r) : "v"(lo), "v"(hi));
  return r;
}

// swap: new_x = {x.low32lanes, y.low32lanes}; new_y = {x.high, y.high}
__device__ __forceinline__ void plswap(unsigned &x, unsigned &y) {
#if __has_builtin(__builtin_amdgcn_permlane32_swap)
  auto r = __builtin_amdgcn_permlane32_swap((int)x, (int)y, false, false);
  x = (unsigned)r[0]; y = (unsigned)r[1];
#else
  const unsigned sx = (unsigned)__shfl_xor((int)x, 32);
  const unsigned sy = (unsigned)__shfl_xor((int)y, 32);
  const bool hi = (threadIdx.x & 63) >= 32;
  const unsigned nx = hi ? sy : x;
  const unsigned ny = hi ? y : sx;
  x = nx; y = ny;
#endif
}

__device__ __forceinline__ void gload16(const unsigned short* g, unsigned short* l) {
  __builtin_amdgcn_global_load_lds(
      (const __attribute__((address_space(1))) unsigned int*)g,
      (__attribute__((address_space(3))) unsigned int*)l, 16, 0, 0);
}

// ---------------- fp32 -> bf16 convert ----------------
__global__ void cvt_bf16(const float* __restrict__ src, unsigned short* __restrict__ dst, int n4) {
  int i = blockIdx.x * blockDim.x + threadIdx.x;
  const int stride = gridDim.x * blockDim.x;
  for (; i < n4; i += stride) {
    const float4 v = reinterpret_cast<const float4*>(src)[i];
    ushort4v o;
    o[0] = f2bf(v.x); o[1] = f2bf(v.y); o[2] = f2bf(v.z); o[3] = f2bf(v.w);
    reinterpret_cast<ushort4v*>(dst)[i] = o;
  }
}

// ---------------- GEMM: C[m,n] = sum_k A[m,k]*Bw[n,k] + bias[n] ----------------
// global_load_lds(16B) staging, linear-fill LDS with inverse-swizzled global source,
// swizzled ds_read fragments (conflict-free). 128x128 tile, BK=64, 4 waves 2x2.
// MODE 0: scatter q (scaled by 0.125*log2e), k, v into [bh][s][64] bf16.
// MODE 1: fp32 out [M][N].
template<int MODE>
__global__ __launch_bounds__(256, 2)
void gemm_bt(const unsigned short* __restrict__ A,
             const unsigned short* __restrict__ Bw,
             const float* __restrict__ bias,
             unsigned short* __restrict__ q_ws,
             unsigned short* __restrict__ k_ws,
             unsigned short* __restrict__ v_ws,
             float* __restrict__ fout,
             int N)
{
  __shared__ __attribute__((aligned(16))) unsigned short As[128 * 64];
  __shared__ __attribute__((aligned(16))) unsigned short Bs[128 * 64];

  const int t = threadIdx.x;
  const int w = t >> 6, lane = t & 63;
  const int g = lane >> 4, c = lane & 15;
  const int wrow = w >> 1, wcol = w & 1;
  const int m0 = blockIdx.y * 128;
  const int n0 = blockIdx.x * 128;

  const int r8 = lane >> 3;                  // row within this wave's 8-row stage block
  const int cgs = (lane & 7) ^ r8;           // inverse-swizzled source chunk

  const f32x4 fz = {0.f, 0.f, 0.f, 0.f};
  f32x4 acc[4][4];
#pragma unroll
  for (int i = 0; i < 4; ++i)
#pragma unroll
    for (int j = 0; j < 4; ++j) acc[i][j] = fz;

  for (int ks = 0; ks < GK; ks += 64) {
    __syncthreads();   // all waves done reading previous tile
#pragma unroll
    for (int i = 0; i < 4; ++i) {
      const int RB = (i * 4 + w) * 8;        // 8-row block base
      gload16(A + (size_t)(m0 + RB + r8) * GK + ks + cgs * 8, &As[RB * 64]);
      gload16(Bw + (size_t)(n0 + RB + r8) * GK + ks + cgs * 8, &Bs[RB * 64]);
    }
    __syncthreads();   // compiler drains vmcnt(0) before barrier -> tile ready
#pragma unroll
    for (int kk = 0; kk < 2; ++kk) {
      short8 af[4], bfr[4];
#pragma unroll
      for (int mi = 0; mi < 4; ++mi) {
        const int row = wrow * 64 + mi * 16 + c;
        af[mi] = *reinterpret_cast<const short8*>(&As[row * 64 + (((kk * 4 + g) ^ (row & 7)) << 3)]);
      }
#pragma unroll
      for (int ni = 0; ni < 4; ++ni) {
        const int row = wcol * 64 + ni * 16 + c;
        bfr[ni] = *reinterpret_cast<const short8*>(&Bs[row * 64 + (((kk * 4 + g) ^ (row & 7)) << 3)]);
      }
#pragma unroll
      for (int mi = 0; mi < 4; ++mi)
#pragma unroll
        for (int ni = 0; ni < 4; ++ni)
          acc[mi][ni] = __builtin_amdgcn_mfma_f32_16x16x32_bf16(af[mi], bfr[ni], acc[mi][ni], 0, 0, 0);
    }
  }

  if (MODE == 0) {
    const int sec = n0 >> 10;  // 0=q 1=k 2=v
    unsigned short* dst = (sec == 0) ? q_ws : ((sec == 1) ? k_ws : v_ws);
    const float qsc = (sec == 0) ? (0.125f * 1.44269504f) : 1.0f;
#pragma unroll
    for (int ni = 0; ni < 4; ++ni) {
      const int n = n0 + wcol * 64 + ni * 16 + c;
      const float bb = bias[n];
      const int hh = (n & 1023) >> 6;
      const int d = n & 63;
#pragma unroll
      for (int mi = 0; mi < 4; ++mi) {
#pragma unroll
        for (int r = 0; r < 4; ++r) {
          const int m = m0 + wrow * 64 + mi * 16 + g * 4 + r;
          const int b = m >> 11, s = m & 2047;
          const float val = (acc[mi][ni][r] + bb) * qsc;
          dst[((size_t)((b * NH + hh) * SEQ + s) << 6) + d] = f2bf(val);
        }
      }
    }
  } else {
#pragma unroll
    for (int ni = 0; ni < 4; ++ni) {
      const int n = n0 + wcol * 64 + ni * 16 + c;
      const float bb = bias[n];
#pragma unroll
      for (int mi = 0; mi < 4; ++mi) {
#pragma unroll
        for (int r = 0; r < 4; ++r) {
          const int m = m0 + wrow * 64 + mi * 16 + g * 4 + r;
          fout[(size_t)m * N + n] = acc[mi][ni][r] + bb;
        }
      }
    }
  }
}

// ---------------- V transpose: [bh][s][64] -> [bh][d][SEQ] ----------------
__global__ __launch_bounds__(256)
void transpose_v(const unsigned short* __restrict__ v, unsigned short* __restrict__ vt) {
  __shared__ unsigned short T[64][72];   // 72*2B = 144B rows (16B aligned, bank-staggered)
  const int t = threadIdx.x;
  const int bh = blockIdx.y, s0 = blockIdx.x * 64;
  const unsigned short* src = v + ((size_t)bh * SEQ + s0) * 64;
#pragma unroll
  for (int rep = 0; rep < 2; ++rep) {
    const int u = rep * 256 + t;
    const int sr = u >> 3, cg = u & 7;
    const short8 x = *reinterpret_cast<const short8*>(src + (size_t)sr * 64 + cg * 8);
    *reinterpret_cast<short8*>(&T[sr][cg * 8]) = x;
  }
  __syncthreads();
  unsigned short* dst = vt + (size_t)bh * 64 * SEQ + s0;
#pragma unroll
  for (int rep = 0; rep < 2; ++rep) {
    const int u = rep * 256 + t;
    const int d = u >> 3, sc8 = u & 7;
    short8 x;
#pragma unroll
    for (int j = 0; j < 8; ++j) x[j] = (short)T[sc8 * 8 + j][d];
    *reinterpret_cast<short8*>(dst + (size_t)d * SEQ + sc8 * 8) = x;
  }
}

// ---------------- flash attention (causal) ----------------
// grid (4, 64): paired 256-row q-tiles {j, 7-j}; 4 waves, wave owns 64 q-rows (2 subtiles).
// K/V^T double-buffered in swizzled LDS; K/V fragments shared by both subtiles.
// Swapped QK^T (mfma(K,Q)); P kept in registers via cvt_pk + permlane32_swap.
__global__ __launch_bounds__(256, 2)
void attn_fwd3(const unsigned short* __restrict__ q_ws,
               const unsigned short* __restrict__ k_ws,
               const unsigned short* __restrict__ vt_ws,
               unsigned short* __restrict__ y_ws)
{
  __shared__ __attribute__((aligned(16))) unsigned short Ks[2][64 * 64];
  __shared__ __attribute__((aligned(16))) unsigned short Vs[2][64 * 64];

  const int t = threadIdx.x;
  const int w = t >> 6, lane = t & 63;
  const int ql = lane & 31, hi = lane >> 5;
  const int bh = blockIdx.y, b = bh >> 4, h = bh & 15;

  const int s_row = t >> 3, s_cg = t & 7;   // stage geometry: 32 rows per rep
  const int so0 = s_row * 64 + ((s_cg ^ (s_row & 7)) << 3);
  const int so1 = (s_row + 32) * 64 + ((s_cg ^ (s_row & 7)) << 3);

  const unsigned short* kbase = k_ws + (size_t)bh * SEQ * 64;
  const unsigned short* vbase = vt_ws + (size_t)bh * 64 * SEQ;

  short8 rk0, rk1, rv0, rv1;
  auto stage_issue = [&](int kt) {
    const unsigned short* kp = kbase + (size_t)kt * 64 * 64;
    rk0 = *reinterpret_cast<const short8*>(kp + (size_t)s_row * 64 + s_cg * 8);
    rk1 = *reinterpret_cast<const short8*>(kp + (size_t)(s_row + 32) * 64 + s_cg * 8);
    const unsigned short* vp = vbase + kt * 64;
    rv0 = *reinterpret_cast<const short8*>(vp + (size_t)s_row * SEQ + s_cg * 8);
    rv1 = *reinterpret_cast<const short8*>(vp + (size_t)(s_row + 32) * SEQ + s_cg * 8);
  };
  auto stage_write = [&](int bi) {
    *reinterpret_cast<short8*>(&Ks[bi][so0]) = rk0;
    *reinterpret_cast<short8*>(&Ks[bi][so1]) = rk1;
    *reinterpret_cast<short8*>(&Vs[bi][so0]) = rv0;
    *reinterpret_cast<short8*>(&Vs[bi][so1]) = rv1;
  };

#pragma unroll 1
  for (int pi = 0; pi < 2; ++pi) {
    const int jt = pi ? (7 - blockIdx.x) : blockIdx.x;
    const int wq0 = jt * 256 + w * 64;       // subtile A rows wq0.., B rows wq0+32..
    const int nkt = 4 * jt + 4;

    const unsigned short* qrA = q_ws + ((size_t)bh * SEQ + (wq0 + ql)) * 64;
    const unsigned short* qrB = qrA + 32 * 64;
    short8 qfA[4], qfB[4];
#pragma unroll
    for (int ks = 0; ks < 4; ++ks) {
      qfA[ks] = *reinterpret_cast<const short8*>(qrA + ks * 16 + hi * 8);
      qfB[ks] = *reinterpret_cast<const short8*>(qrB + ks * 16 + hi * 8);
    }

    f32x16 oA0, oA1, oB0, oB1;
#pragma unroll
    for (int i = 0; i < 16; ++i) { oA0[i] = 0.f; oA1[i] = 0.f; oB0[i] = 0.f; oB1[i] = 0.f; }
    float mA = -1e30f, lA = 0.f, mB = -1e30f, lB = 0.f;

    stage_issue(0);
    stage_write(0);

    // softmax + pack P into registers (pa[4] = PV A-operand fragments)
    auto softmax_pack = [&](f32x16& s0, f32x16& s1, float& m_run, float& lsum,
                            f32x16& o0, f32x16& o1, short8* pa) {
      float tm = -1e30f;
#pragma unroll
      for (int r = 0; r < 16; ++r) tm = fmaxf(tm, fmaxf(s0[r], s1[r]));
      tm = fmaxf(tm, __shfl_xor(tm, 32));
      if (__any(tm > m_run + 10.0f)) {
        const float m_new = fmaxf(m_run, tm);
        const float al = __builtin_amdgcn_exp2f(m_run - m_new);
        m_run = m_new;
        lsum *= al;
#pragma unroll
        for (int r = 0; r < 16; ++r) {
          const int qq = (r & 3) + 8 * (r >> 2) + 4 * hi;
          const float ar = __shfl(al, qq);
          o0[r] *= ar; o1[r] *= ar;
        }
      }
      float psum = 0.f;
      unsigned W[16];
#pragma unroll
      for (int half = 0; half < 2; ++half) {
#pragma unroll
        for (int gr = 0; gr < 4; ++gr) {
          const float v0 = (half ? s1[gr * 4 + 0] : s0[gr * 4 + 0]) - m_run;
          const float v1 = (half ? s1[gr * 4 + 1] : s0[gr * 4 + 1]) - m_run;
          const float v2 = (half ? s1[gr * 4 + 2] : s0[gr * 4 + 2]) - m_run;
          const float v3 = (half ? s1[gr * 4 + 3] : s0[gr * 4 + 3]) - m_run;
          const float p0 = __builtin_amdgcn_exp2f(v0);
          const float p1 = __builtin_amdgcn_exp2f(v1);
          const float p2 = __builtin_amdgcn_exp2f(v2);
          const float p3 = __builtin_amdgcn_exp2f(v3);
          psum += (p0 + p1) + (p2 + p3);
          W[half * 8 + 2 * gr]     = cvtpk_bf16(p0, p1);   // A_g
          W[half * 8 + 2 * gr + 1] = cvtpk_bf16(p2, p3);   // B_g
        }
      }
      lsum += psum;
      // group-pair swaps: (g even, g odd) -> quad [A_e, B_e, A_e', B_e'] per lane-half
#pragma unroll
      for (int q4 = 0; q4 < 4; ++q4) {
        unsigned a0 = W[q4 * 4 + 0], a1 = W[q4 * 4 + 2];   // A_even, A_odd
        unsigned b0 = W[q4 * 4 + 1], b1 = W[q4 * 4 + 3];   // B_even, B_odd
        plswap(a0, a1);
        plswap(b0, b1);
        uint4v pk; pk[0] = a0; pk[1] = b0; pk[2] = a1; pk[3] = b1;
        pa[q4] = __builtin_bit_cast(short8, pk);
      }
    };

#pragma unroll 1
    for (int kt = 0; kt < nkt; ++kt) {
      const bool more = (kt + 1) < nkt;
      if (more) stage_issue(kt + 1);
      __syncthreads();
      const int cur = kt & 1;
      const int kt64 = kt * 64;

      if (kt64 <= wq0 + 63) {   // wave active
        // K fragments (shared by both subtiles)
        short8 kfl[4], kfh[4];
#pragma unroll
        for (int ks = 0; ks < 4; ++ks) {
          kfl[ks] = *reinterpret_cast<const short8*>(
              &Ks[cur][ql * 64 + (((2 * ks + hi) ^ (ql & 7)) << 3)]);
          kfh[ks] = *reinterpret_cast<const short8*>(
              &Ks[cur][(32 + ql) * 64 + (((2 * ks + hi) ^ (ql & 7)) << 3)]);
        }
        const bool actA = kt64 <= wq0 + 31;
        short8 paA[4], paB[4];

        // ---- subtile A ----
        if (actA) {
          f32x16 s0, s1;
#pragma unroll
          for (int i = 0; i < 16; ++i) { s0[i] = 0.f; s1[i] = 0.f; }
#pragma unroll
          for (int ks = 0; ks < 4; ++ks) {
            s0 = __builtin_amdgcn_mfma_f32_32x32x16_bf16(kfl[ks], qfA[ks], s0, 0, 0, 0);
            s1 = __builtin_amdgcn_mfma_f32_32x32x16_bf16(kfh[ks], qfA[ks], s1, 0, 0, 0);
          }
          if (kt64 + 63 > wq0) {
            const int gq = wq0 + ql;
#pragma unroll
            for (int r = 0; r < 16; ++r) {
              const int krow = (r & 3) + 8 * (r >> 2) + 4 * hi;
              if (kt64 + krow > gq)      s0[r] = -1e30f;
              if (kt64 + 32 + krow > gq) s1[r] = -1e30f;
            }
          }
          softmax_pack(s0, s1, mA, lA, oA0, oA1, paA);
        }
        // ---- subtile B ----
        {
          f32x16 s0, s1;
#pragma unroll
          for (int i = 0; i < 16; ++i) { s0[i] = 0.f; s1[i] = 0.f; }
#pragma unroll
          for (int ks = 0; ks < 4; ++ks) {
            s0 = __builtin_amdgcn_mfma_f32_32x32x16_bf16(kfl[ks], qfB[ks], s0, 0, 0, 0);
            s1 = __builtin_amdgcn_mfma_f32_32x32x16_bf16(kfh[ks], qfB[ks], s1, 0, 0, 0);
          }
          if (kt64 + 63 > wq0 + 32) {
            const int gq = wq0 + 32 + ql;
#pragma unroll
            for (int r = 0; r < 16; ++r) {
              const int krow = (r & 3) + 8 * (r >> 2) + 4 * hi;
              if (kt64 + krow > gq)      s0[r] = -1e30f;
              if (kt64 + 32 + krow > gq) s1[r] = -1e30f;
            }
          }
          softmax_pack(s0, s1, mB, lB, oB0, oB1, paB);
        }
        // ---- PV (V fragments shared) ----
#pragma unroll
        for (int ks = 0; ks < 4; ++ks) {
          const short8 vfl = *reinterpret_cast<const short8*>(
              &Vs[cur][ql * 64 + (((2 * ks + hi) ^ (ql & 7)) << 3)]);
          const short8 vfh = *reinterpret_cast<const short8*>(
              &Vs[cur][(32 + ql) * 64 + (((2 * ks + hi) ^ (ql & 7)) << 3)]);
          oB0 = __builtin_amdgcn_mfma_f32_32x32x16_bf16(paB[ks], vfl, oB0, 0, 0, 0);
          oB1 = __builtin_amdgcn_mfma_f32_32x32x16_bf16(paB[ks], vfh, oB1, 0, 0, 0);
          if (actA) {
            oA0 = __builtin_amdgcn_mfma_f32_32x32x16_bf16(paA[ks], vfl, oA0, 0, 0, 0);
            oA1 = __builtin_amdgcn_mfma_f32_32x32x16_bf16(paA[ks], vfh, oA1, 0, 0, 0);
          }
        }
      }
      if (more) stage_write((kt + 1) & 1);
    }

    // ---- epilogue ----
    auto fin = [&](f32x16& o0, f32x16& o1, float lsum, int qbase) {
      lsum += __shfl_xor(lsum, 32);
      const float linv = 1.f / lsum;
#pragma unroll
      for (int r = 0; r < 16; ++r) {
        const int qq = (r & 3) + 8 * (r >> 2) + 4 * hi;
        const float lr = __shfl(linv, qq);
        const size_t rowo = ((size_t)b * SEQ + (qbase + qq)) * 1024 + h * 64;
        y_ws[rowo + ql]      = f2bf(o0[r] * lr);
        y_ws[rowo + 32 + ql] = f2bf(o1[r] * lr);
      }
    };
    fin(oA0, oA1, lA, wq0);
    fin(oB0, oB1, lB, wq0 + 32);
    __syncthreads();   // protect LDS buffers before next pass prologue
  }
}

extern "C" void kernel_launch(void* const* d_in, const int* in_sizes, int n_in,
                              void* d_out, int out_size, void* d_ws, size_t ws_size,
                              hipStream_t stream)
{
  (void)in_sizes; (void)n_in; (void)out_size; (void)ws_size;
  const float* x     = (const float*)d_in[0];
  const float* W_qkv = (const float*)d_in[1];
  const float* b_qkv = (const float*)d_in[2];
  const float* W_out = (const float*)d_in[3];
  const float* b_out = (const float*)d_in[4];
  float* out = (float*)d_out;

  unsigned short* ws      = (unsigned short*)d_ws;
  unsigned short* x_bf    = ws;                                   // 8192*1024 (reused as vt later)
  unsigned short* wqkv_bf = x_bf    + (size_t)8192 * 1024;        // 3072*1024
  unsigned short* wout_bf = wqkv_bf + (size_t)3072 * 1024;        // 1024*1024
  unsigned short* q_ws    = wout_bf + (size_t)1024 * 1024;        // [bh][s][64]
  unsigned short* k_ws    = q_ws    + (size_t)64 * SEQ * 64;
  unsigned short* v_ws    = k_ws    + (size_t)64 * SEQ * 64;
  unsigned short* y_ws    = v_ws    + (size_t)64 * SEQ * 64;      // 8192*1024
  unsigned short* vt_ws   = x_bf;   // x_bf dead after qkv GEMM; vt fits exactly (16MB)

  cvt_bf16<<<2048, 256, 0, stream>>>(x,     x_bf,    (8192 * 1024) / 4);
  cvt_bf16<<<1024, 256, 0, stream>>>(W_qkv, wqkv_bf, (3072 * 1024) / 4);
  cvt_bf16<<<512,  256, 0, stream>>>(W_out, wout_bf, (1024 * 1024) / 4);

  gemm_bt<0><<<dim3(24, 64), 256, 0, stream>>>(x_bf, wqkv_bf, b_qkv, q_ws, k_ws, v_ws, nullptr, 3072);
  transpose_v<<<dim3(SEQ / 64, 64), 256, 0, stream>>>(v_ws, vt_ws);
  attn_fwd3<<<dim3(4, 64), 256, 0, stream>>>(q_ws, k_ws, vt_ws, y_ws);
  gemm_bt<1><<<dim3(8, 64), 256, 0, stream>>>(y_ws, wout_bf, b_out, nullptr, nullptr, nullptr, out, 1024);
}

// Round 4
// 180.901 us; speedup vs baseline: 1.0703x; 1.0703x over previous
//
#include <hip/hip_runtime.h>
#include <stdint.h>
#include <stddef.h>

typedef __attribute__((ext_vector_type(8))) short short8;
typedef __attribute__((ext_vector_type(4))) float f32x4;
typedef __attribute__((ext_vector_type(16))) float f32x16;
typedef __attribute__((ext_vector_type(4))) unsigned short ushort4v;
typedef __attribute__((ext_vector_type(4))) unsigned int uint4v;

#define SEQ   2048
#define NH    16
#define BATCH 4
#define GK    1024

__device__ __forceinline__ unsigned short f2bf(float f) {
  union { float f; unsigned int u; } v; v.f = f;
  unsigned int u = v.u;
  u += 0x7fffu + ((u >> 16) & 1u);
  return (unsigned short)(u >> 16);
}

__device__ __forceinline__ unsigned cvtpk_bf16(float lo, float hi) {
  unsigned r;
  asm("v_cvt_pk_bf16_f32 %0, %1, %2" : "=v"(r) : "v"(lo), "v"(hi));
  return r;
}

// swap halves: x' = {x.lanes0-31, y.lanes0-31}; y' = {x.lanes32-63, y.lanes32-63}
__device__ __forceinline__ void plswap(unsigned &x, unsigned &y) {
#if __has_builtin(__builtin_amdgcn_permlane32_swap)
  auto r = __builtin_amdgcn_permlane32_swap((int)x, (int)y, false, false);
  x = (unsigned)r[0]; y = (unsigned)r[1];
#else
  const unsigned sx = (unsigned)__shfl_xor((int)x, 32);
  const unsigned sy = (unsigned)__shfl_xor((int)y, 32);
  const bool hi = (threadIdx.x & 63) >= 32;
  const unsigned nx = hi ? sy : x;
  const unsigned ny = hi ? y : sx;
  x = nx; y = ny;
#endif
}

__device__ __forceinline__ void gload16(const unsigned short* g, unsigned short* l) {
  __builtin_amdgcn_global_load_lds(
      (const __attribute__((address_space(1))) unsigned int*)g,
      (__attribute__((address_space(3))) unsigned int*)l, 16, 0, 0);
}

// ---------------- fp32 -> bf16 convert ----------------
__global__ void cvt_bf16(const float* __restrict__ src, unsigned short* __restrict__ dst, int n4) {
  int i = blockIdx.x * blockDim.x + threadIdx.x;
  const int stride = gridDim.x * blockDim.x;
  for (; i < n4; i += stride) {
    const float4 v = reinterpret_cast<const float4*>(src)[i];
    ushort4v o;
    o[0] = f2bf(v.x); o[1] = f2bf(v.y); o[2] = f2bf(v.z); o[3] = f2bf(v.w);
    reinterpret_cast<ushort4v*>(dst)[i] = o;
  }
}

// ---------------- GEMM: C[m,n] = sum_k A[m,k]*Bw[n,k] + bias[n] ----------------
template<int MODE>
__global__ __launch_bounds__(256, 2)
void gemm_bt(const unsigned short* __restrict__ A,
             const unsigned short* __restrict__ Bw,
             const float* __restrict__ bias,
             unsigned short* __restrict__ q_ws,
             unsigned short* __restrict__ k_ws,
             unsigned short* __restrict__ v_ws,
             float* __restrict__ fout,
             int N)
{
  __shared__ __attribute__((aligned(16))) unsigned short As[128 * 64];
  __shared__ __attribute__((aligned(16))) unsigned short Bs[128 * 64];

  const int t = threadIdx.x;
  const int w = t >> 6, lane = t & 63;
  const int g = lane >> 4, c = lane & 15;
  const int wrow = w >> 1, wcol = w & 1;
  const int m0 = blockIdx.y * 128;
  const int n0 = blockIdx.x * 128;

  const int r8 = lane >> 3;
  const int cgs = (lane & 7) ^ r8;

  const f32x4 fz = {0.f, 0.f, 0.f, 0.f};
  f32x4 acc[4][4];
#pragma unroll
  for (int i = 0; i < 4; ++i)
#pragma unroll
    for (int j = 0; j < 4; ++j) acc[i][j] = fz;

  for (int ks = 0; ks < GK; ks += 64) {
    __syncthreads();
#pragma unroll
    for (int i = 0; i < 4; ++i) {
      const int RB = (i * 4 + w) * 8;
      gload16(A + (size_t)(m0 + RB + r8) * GK + ks + cgs * 8, &As[RB * 64]);
      gload16(Bw + (size_t)(n0 + RB + r8) * GK + ks + cgs * 8, &Bs[RB * 64]);
    }
    __syncthreads();
#pragma unroll
    for (int kk = 0; kk < 2; ++kk) {
      short8 af[4], bfr[4];
#pragma unroll
      for (int mi = 0; mi < 4; ++mi) {
        const int row = wrow * 64 + mi * 16 + c;
        af[mi] = *reinterpret_cast<const short8*>(&As[row * 64 + (((kk * 4 + g) ^ (row & 7)) << 3)]);
      }
#pragma unroll
      for (int ni = 0; ni < 4; ++ni) {
        const int row = wcol * 64 + ni * 16 + c;
        bfr[ni] = *reinterpret_cast<const short8*>(&Bs[row * 64 + (((kk * 4 + g) ^ (row & 7)) << 3)]);
      }
#pragma unroll
      for (int mi = 0; mi < 4; ++mi)
#pragma unroll
        for (int ni = 0; ni < 4; ++ni)
          acc[mi][ni] = __builtin_amdgcn_mfma_f32_16x16x32_bf16(af[mi], bfr[ni], acc[mi][ni], 0, 0, 0);
    }
  }

  if (MODE == 0) {
    const int sec = n0 >> 10;  // 0=q 1=k 2=v
    unsigned short* dst = (sec == 0) ? q_ws : ((sec == 1) ? k_ws : v_ws);
    const float qsc = (sec == 0) ? (0.125f * 1.44269504f) : 1.0f;
#pragma unroll
    for (int ni = 0; ni < 4; ++ni) {
      const int n = n0 + wcol * 64 + ni * 16 + c;
      const float bb = bias[n];
      const int hh = (n & 1023) >> 6;
      const int d = n & 63;
#pragma unroll
      for (int mi = 0; mi < 4; ++mi) {
#pragma unroll
        for (int r = 0; r < 4; ++r) {
          const int m = m0 + wrow * 64 + mi * 16 + g * 4 + r;
          const int b = m >> 11, s = m & 2047;
          const float val = (acc[mi][ni][r] + bb) * qsc;
          dst[((size_t)((b * NH + hh) * SEQ + s) << 6) + d] = f2bf(val);
        }
      }
    }
  } else {
#pragma unroll
    for (int ni = 0; ni < 4; ++ni) {
      const int n = n0 + wcol * 64 + ni * 16 + c;
      const float bb = bias[n];
#pragma unroll
      for (int mi = 0; mi < 4; ++mi) {
#pragma unroll
        for (int r = 0; r < 4; ++r) {
          const int m = m0 + wrow * 64 + mi * 16 + g * 4 + r;
          fout[(size_t)m * N + n] = acc[mi][ni][r] + bb;
        }
      }
    }
  }
}

// ---------------- V transpose: [bh][s][64] -> [bh][d][SEQ] ----------------
__global__ __launch_bounds__(256)
void transpose_v(const unsigned short* __restrict__ v, unsigned short* __restrict__ vt) {
  __shared__ unsigned short T[64][72];
  const int t = threadIdx.x;
  const int bh = blockIdx.y, s0 = blockIdx.x * 64;
  const unsigned short* src = v + ((size_t)bh * SEQ + s0) * 64;
#pragma unroll
  for (int rep = 0; rep < 2; ++rep) {
    const int u = rep * 256 + t;
    const int sr = u >> 3, cg = u & 7;
    const short8 x = *reinterpret_cast<const short8*>(src + (size_t)sr * 64 + cg * 8);
    *reinterpret_cast<short8*>(&T[sr][cg * 8]) = x;
  }
  __syncthreads();
  unsigned short* dst = vt + (size_t)bh * 64 * SEQ + s0;
#pragma unroll
  for (int rep = 0; rep < 2; ++rep) {
    const int u = rep * 256 + t;
    const int d = u >> 3, sc8 = u & 7;
    short8 x;
#pragma unroll
    for (int j = 0; j < 8; ++j) x[j] = (short)T[sc8 * 8 + j][d];
    *reinterpret_cast<short8*>(dst + (size_t)d * SEQ + sc8 * 8) = x;
  }
}

// ---------------- flash attention (causal), 8-wave blocks, 4 waves/SIMD ----------------
// grid (8, 64): block = 256-row q-tile jt (balanced map), 8 waves x 32 q-rows.
// K/V^T double-buffered swizzled LDS (32KB); swapped QK^T; register-P softmax
// (cvt_pk + permlane32_swap); defer-max; exp2-domain (log2e folded into q).
__global__ __launch_bounds__(512, 4)
void attn_fwd4(const unsigned short* __restrict__ q_ws,
               const unsigned short* __restrict__ k_ws,
               const unsigned short* __restrict__ vt_ws,
               unsigned short* __restrict__ y_ws)
{
  __shared__ __attribute__((aligned(16))) unsigned short Ks[2][64 * 64];
  __shared__ __attribute__((aligned(16))) unsigned short Vs[2][64 * 64];

  const int t = threadIdx.x;
  const int w = t >> 6, lane = t & 63;
  const int ql = lane & 31, hi = lane >> 5;
  const int bh = blockIdx.y, b = bh >> 4, h = bh & 15;
  // per-CU balance heuristic: blocks c and c+256 share bx, differ in by>=32
  const int jt = (blockIdx.y >= 32) ? (7 - (int)blockIdx.x) : (int)blockIdx.x;
  const int wq0 = jt * 256 + w * 32;
  const int nkt = 4 * jt + 4;

  const int s_row = t >> 3, s_cg = t & 7;   // 512 threads cover 64 rows x 8 chunks
  const int so = s_row * 64 + ((s_cg ^ (s_row & 7)) << 3);

  const unsigned short* kbase = k_ws + (size_t)bh * SEQ * 64;
  const unsigned short* vbase = vt_ws + (size_t)bh * 64 * SEQ;

  short8 rk, rv;
  auto stage_issue = [&](int kt) {
    rk = *reinterpret_cast<const short8*>(kbase + (size_t)kt * 4096 + s_row * 64 + s_cg * 8);
    rv = *reinterpret_cast<const short8*>(vbase + (size_t)s_row * SEQ + kt * 64 + s_cg * 8);
  };
  auto stage_write = [&](int bi) {
    *reinterpret_cast<short8*>(&Ks[bi][so]) = rk;
    *reinterpret_cast<short8*>(&Vs[bi][so]) = rv;
  };

  // Q fragments: lane holds Q[q = wq0+ql][d = 16*ks + 8*hi + j]
  const unsigned short* qr = q_ws + ((size_t)bh * SEQ + (wq0 + ql)) * 64;
  short8 qf[4];
#pragma unroll
  for (int ks = 0; ks < 4; ++ks)
    qf[ks] = *reinterpret_cast<const short8*>(qr + ks * 16 + hi * 8);

  f32x16 o0, o1;
#pragma unroll
  for (int i = 0; i < 16; ++i) { o0[i] = 0.f; o1[i] = 0.f; }
  float m_run = -1e30f, lsum = 0.f;

  stage_issue(0);
  stage_write(0);

#pragma unroll 1
  for (int kt = 0; kt < nkt; ++kt) {
    const bool more = (kt + 1) < nkt;
    if (more) stage_issue(kt + 1);     // issue-early (T14)
    __syncthreads();
    const int cur = kt & 1;
    const int kt64 = kt * 64;

    if (kt64 <= wq0 + 31) {            // wave-uniform activity gate
      // K fragments
      short8 kfl[4], kfh[4];
#pragma unroll
      for (int ks = 0; ks < 4; ++ks) {
        kfl[ks] = *reinterpret_cast<const short8*>(
            &Ks[cur][ql * 64 + (((2 * ks + hi) ^ (ql & 7)) << 3)]);
        kfh[ks] = *reinterpret_cast<const short8*>(
            &Ks[cur][(32 + ql) * 64 + (((2 * ks + hi) ^ (ql & 7)) << 3)]);
      }
      // ---- QK^T (swapped: D[key][q], col=lane&31=q) ----
      f32x16 s0, s1;
#pragma unroll
      for (int i = 0; i < 16; ++i) { s0[i] = 0.f; s1[i] = 0.f; }
      __builtin_amdgcn_s_setprio(1);
#pragma unroll
      for (int ks = 0; ks < 4; ++ks) {
        s0 = __builtin_amdgcn_mfma_f32_32x32x16_bf16(kfl[ks], qf[ks], s0, 0, 0, 0);
        s1 = __builtin_amdgcn_mfma_f32_32x32x16_bf16(kfh[ks], qf[ks], s1, 0, 0, 0);
      }
      __builtin_amdgcn_s_setprio(0);
      // ---- causal mask (diagonal straddle only) ----
      if (kt64 + 63 > wq0) {
        const int gq = wq0 + ql;
#pragma unroll
        for (int r = 0; r < 16; ++r) {
          const int krow = (r & 3) + 8 * (r >> 2) + 4 * hi;
          if (kt64 + krow > gq)      s0[r] = -1e30f;
          if (kt64 + 32 + krow > gq) s1[r] = -1e30f;
        }
      }
      // ---- online softmax (log2 domain), defer-max THR=10 ----
      float tm = -1e30f;
#pragma unroll
      for (int r = 0; r < 16; ++r) tm = fmaxf(tm, fmaxf(s0[r], s1[r]));
      tm = fmaxf(tm, __shfl_xor(tm, 32));
      if (__any(tm > m_run + 10.0f)) {
        const float m_new = fmaxf(m_run, tm);
        const float al = __builtin_amdgcn_exp2f(m_run - m_new);
        m_run = m_new;
        lsum *= al;
#pragma unroll
        for (int r = 0; r < 16; ++r) {
          const int qq = (r & 3) + 8 * (r >> 2) + 4 * hi;
          const float ar = __shfl(al, qq);
          o0[r] *= ar; o1[r] *= ar;
        }
      }
      float psum = 0.f;
      unsigned W[16];
#pragma unroll
      for (int half = 0; half < 2; ++half) {
#pragma unroll
        for (int gr = 0; gr < 4; ++gr) {
          const float v0 = (half ? s1[gr * 4 + 0] : s0[gr * 4 + 0]) - m_run;
          const float v1 = (half ? s1[gr * 4 + 1] : s0[gr * 4 + 1]) - m_run;
          const float v2 = (half ? s1[gr * 4 + 2] : s0[gr * 4 + 2]) - m_run;
          const float v3 = (half ? s1[gr * 4 + 3] : s0[gr * 4 + 3]) - m_run;
          const float p0 = __builtin_amdgcn_exp2f(v0);
          const float p1 = __builtin_amdgcn_exp2f(v1);
          const float p2 = __builtin_amdgcn_exp2f(v2);
          const float p3 = __builtin_amdgcn_exp2f(v3);
          psum += (p0 + p1) + (p2 + p3);
          W[half * 8 + 2 * gr]     = cvtpk_bf16(p0, p1);
          W[half * 8 + 2 * gr + 1] = cvtpk_bf16(p2, p3);
        }
      }
      lsum += psum;
      // redistribute P into PV A-operand fragments (register-only)
      short8 pa[4];
#pragma unroll
      for (int q4 = 0; q4 < 4; ++q4) {
        unsigned a0 = W[q4 * 4 + 0], a1 = W[q4 * 4 + 2];
        unsigned b0 = W[q4 * 4 + 1], b1 = W[q4 * 4 + 3];
        plswap(a0, a1);
        plswap(b0, b1);
        uint4v pk; pk[0] = a0; pk[1] = b0; pk[2] = a1; pk[3] = b1;
        pa[q4] = __builtin_bit_cast(short8, pk);
      }
      // ---- PV ----
      __builtin_amdgcn_s_setprio(1);
#pragma unroll
      for (int ks = 0; ks < 4; ++ks) {
        const short8 vfl = *reinterpret_cast<const short8*>(
            &Vs[cur][ql * 64 + (((2 * ks + hi) ^ (ql & 7)) << 3)]);
        const short8 vfh = *reinterpret_cast<const short8*>(
            &Vs[cur][(32 + ql) * 64 + (((2 * ks + hi) ^ (ql & 7)) << 3)]);
        o0 = __builtin_amdgcn_mfma_f32_32x32x16_bf16(pa[ks], vfl, o0, 0, 0, 0);
        o1 = __builtin_amdgcn_mfma_f32_32x32x16_bf16(pa[ks], vfh, o1, 0, 0, 0);
      }
      __builtin_amdgcn_s_setprio(0);
    }
    if (more) stage_write((kt + 1) & 1);   // write-late (T14)
  }

  // ---- epilogue ----
  lsum += __shfl_xor(lsum, 32);
  const float linv = 1.f / lsum;
#pragma unroll
  for (int r = 0; r < 16; ++r) {
    const int qq = (r & 3) + 8 * (r >> 2) + 4 * hi;
    const float lr = __shfl(linv, qq);
    const size_t rowo = ((size_t)b * SEQ + (wq0 + qq)) * 1024 + h * 64;
    y_ws[rowo + ql]      = f2bf(o0[r] * lr);
    y_ws[rowo + 32 + ql] = f2bf(o1[r] * lr);
  }
}

extern "C" void kernel_launch(void* const* d_in, const int* in_sizes, int n_in,
                              void* d_out, int out_size, void* d_ws, size_t ws_size,
                              hipStream_t stream)
{
  (void)in_sizes; (void)n_in; (void)out_size; (void)ws_size;
  const float* x     = (const float*)d_in[0];
  const float* W_qkv = (const float*)d_in[1];
  const float* b_qkv = (const float*)d_in[2];
  const float* W_out = (const float*)d_in[3];
  const float* b_out = (const float*)d_in[4];
  float* out = (float*)d_out;

  unsigned short* ws      = (unsigned short*)d_ws;
  unsigned short* x_bf    = ws;
  unsigned short* wqkv_bf = x_bf    + (size_t)8192 * 1024;
  unsigned short* wout_bf = wqkv_bf + (size_t)3072 * 1024;
  unsigned short* q_ws    = wout_bf + (size_t)1024 * 1024;
  unsigned short* k_ws    = q_ws    + (size_t)64 * SEQ * 64;
  unsigned short* v_ws    = k_ws    + (size_t)64 * SEQ * 64;
  unsigned short* y_ws    = v_ws    + (size_t)64 * SEQ * 64;
  unsigned short* vt_ws   = x_bf;   // x_bf dead after qkv GEMM

  cvt_bf16<<<2048, 256, 0, stream>>>(x,     x_bf,    (8192 * 1024) / 4);
  cvt_bf16<<<1024, 256, 0, stream>>>(W_qkv, wqkv_bf, (3072 * 1024) / 4);
  cvt_bf16<<<512,  256, 0, stream>>>(W_out, wout_bf, (1024 * 1024) / 4);

  gemm_bt<0><<<dim3(24, 64), 256, 0, stream>>>(x_bf, wqkv_bf, b_qkv, q_ws, k_ws, v_ws, nullptr, 3072);
  transpose_v<<<dim3(SEQ / 64, 64), 256, 0, stream>>>(v_ws, vt_ws);
  attn_fwd4<<<dim3(8, 64), 512, 0, stream>>>(q_ws, k_ws, vt_ws, y_ws);
  gemm_bt<1><<<dim3(8, 64), 256, 0, stream>>>(y_ws, wout_bf, b_out, nullptr, nullptr, nullptr, out, 1024);
}